// Round 8
// baseline (209.793 us; speedup 1.0000x reference)
//
#include <hip/hip_runtime.h>
#include <math.h>

#define TTOK 8192
#define DIM  2048
#define NH   1024

// ---- workspace layout (float offsets) ----
// part1 [8192][32][16] = 4.2M floats lives inside the 8.4M-float alias region
// that part6 [256][16][2048] later reuses (part1 dead after KB). Total 34.9 MB.
#define OFF_ALIAS   0u           // max(part1, part6) = 8388608 floats
#define OFF_NUM     8388608u     // [8192][16]
#define OFF_COMBINE 8519680u     // [8192][16]
#define OFF_CSUM    8650752u     // [128][16]
#define OFF_MUSUM   8652800u     // [128][16]
#define OFF_ENT     8654848u     // [128]
#define OFF_SRAW    8654976u     // [16][2048]
#define OFF_HBUF    8687744u     // [16][1024]
#define OFF_SLOT    8704128u     // [16][2048]  -> end 8736896 floats = 34.9 MB

// ---- d_out layout (float offsets) ----
#define O_OUT   0u
#define O_LOSS  16777216u
#define O_GATE  16777217u
#define O_TOPI  16908289u
#define O_TOPW  16924673u
#define O_MU    16941057u
#define O_ENTR  16941073u
#define O_DISP  16941074u

__device__ __forceinline__ float wave_sum(float v){
  #pragma unroll
  for (int o=1;o<64;o<<=1) v += __shfl_xor(v,o,64);
  return v;
}

// KA: logits partials, token-major part1[t][32kc][16]. grid 1024 = 64tb(128tok) x 16kc2;
// thread = (token, kc-half): 16 waves/CU, Wd loads wave-uniform (scalar).
__global__ __launch_bounds__(256) void ka_logits(const float* __restrict__ x,
                                                 const float* __restrict__ Wd,
                                                 float* __restrict__ part1){
  const int tb  = blockIdx.x >> 4;
  const int kc2 = blockIdx.x & 15;
  const int tl  = threadIdx.x & 127;
  const int kch = threadIdx.x >> 7;              // uniform per wave
  const int kcg = kc2*2 + kch;                   // 0..31, 64-float chunk
  const int t   = tb*128 + tl;
  const float4* __restrict__ xr = (const float4*)(x + (size_t)t*DIM + kcg*64);
  float acc[16];
  #pragma unroll
  for (int e=0;e<16;e++) acc[e]=0.f;
  #pragma unroll
  for (int k4=0;k4<16;k4++){
    float4 xv = xr[k4];
    #pragma unroll
    for (int e=0;e<16;e++){
      float4 w = *(const float4*)(Wd + e*DIM + kcg*64 + k4*4);
      acc[e] += xv.x*w.x + xv.y*w.y + xv.z*w.z + xv.w*w.w;
    }
  }
  float4* po = (float4*)(part1 + ((size_t)t*32 + kcg)*16);
  po[0]=make_float4(acc[0],acc[1],acc[2],acc[3]);
  po[1]=make_float4(acc[4],acc[5],acc[6],acc[7]);
  po[2]=make_float4(acc[8],acc[9],acc[10],acc[11]);
  po[3]=make_float4(acc[12],acc[13],acc[14],acc[15]);
}

// KB: reduce part1 (contiguous 2KB/token) -> logits; num=exp; csum partials;
// row softmax outputs. grid 128 x 256 (64 tok/blk).
__global__ __launch_bounds__(256) void kb_router(const float* __restrict__ part1,
    float* __restrict__ num, float* __restrict__ csum_part,
    float* __restrict__ combine, float* __restrict__ gate_out,
    float* __restrict__ topi_out, float* __restrict__ topw_out,
    float* __restrict__ musum_part, float* __restrict__ ent_part){
  const int tid = threadIdx.x;
  const int i = blockIdx.x*256 + tid;            // (t,q): t=i>>2, q=i&3
  const float4* p1 = (const float4*)part1;       // token row = 128 float4
  const size_t base = (size_t)(i>>2)*128 + (i&3);
  float4 s = make_float4(0,0,0,0);
  #pragma unroll
  for (int kc=0;kc<32;kc++){
    float4 v = p1[base + kc*4];                  // base + imm offset, contiguous row
    s.x+=v.x; s.y+=v.y; s.z+=v.z; s.w+=v.w;
  }
  float4 n4 = make_float4(expf(s.x),expf(s.y),expf(s.z),expf(s.w));
  ((float4*)num)[i] = n4;
  __shared__ float Lg[64][20];
  const int tl = tid>>2, q = tid&3;
  *(float4*)(&Lg[tl][q*4]) = s;
  float4 n = n4;
  #pragma unroll
  for (int o=4;o<64;o<<=1){
    n.x += __shfl_xor(n.x,o,64); n.y += __shfl_xor(n.y,o,64);
    n.z += __shfl_xor(n.z,o,64); n.w += __shfl_xor(n.w,o,64);
  }
  __shared__ float4 red[4][4];
  const int w = tid>>6, lane = tid&63;
  if (lane<4) red[w][lane] = n;
  __syncthreads();
  if (tid<4){
    float4 a=red[0][tid],b=red[1][tid],c=red[2][tid],d=red[3][tid];
    *(float4*)(csum_part + blockIdx.x*16 + tid*4) =
      make_float4(a.x+b.x+c.x+d.x, a.y+b.y+c.y+d.y, a.z+b.z+c.z+d.z, a.w+b.w+c.w+d.w);
  }
  if (tid < 64){
    const int gt = blockIdx.x*64 + tid;
    float l[16];
    #pragma unroll
    for (int e=0;e<16;e++) l[e] = Lg[tid][e];
    float m = l[0];
    #pragma unroll
    for (int e=1;e<16;e++) m = fmaxf(m,l[e]);
    float c[16]; float sm=0.f;
    #pragma unroll
    for (int e=0;e<16;e++){ c[e]=expf(l[e]-m); sm+=c[e]; }
    float inv = 1.f/sm;
    #pragma unroll
    for (int e=0;e<16;e++) c[e]*=inv;
    float4* co = (float4*)(combine + (size_t)gt*16);
    co[0]=make_float4(c[0],c[1],c[2],c[3]);   co[1]=make_float4(c[4],c[5],c[6],c[7]);
    co[2]=make_float4(c[8],c[9],c[10],c[11]); co[3]=make_float4(c[12],c[13],c[14],c[15]);
    float* go = gate_out + (size_t)gt*16;
    #pragma unroll
    for (int e=0;e<16;e++) go[e]=c[e];
    float v0=-1.f, v1=-1.f; int i0=0, i1=0;
    #pragma unroll
    for (int e=0;e<16;e++){
      float ce=c[e];
      if (ce>v0){ v1=v0; i1=i0; v0=ce; i0=e; }
      else if (ce>v1){ v1=ce; i1=e; }
    }
    float dn = fmaxf(v0+v1, 1e-8f);
    topi_out[(size_t)gt*2+0]=(float)i0; topi_out[(size_t)gt*2+1]=(float)i1;
    topw_out[(size_t)gt*2+0]=v0/dn;     topw_out[(size_t)gt*2+1]=v1/dn;
    float ent=0.f;
    #pragma unroll
    for (int e=0;e<16;e++) ent -= c[e]*logf(c[e]+1e-8f);
    #pragma unroll
    for (int e=0;e<16;e++){
      float v = wave_sum(c[e]);
      if (tid==0) musum_part[blockIdx.x*16+e] = v;
    }
    float ve = wave_sum(ent);
    if (tid==0) ent_part[blockIdx.x] = ve;
  }
}

// KD: slot_in partials + dispatch + block0 finalize. grid 512 = 256tc(32tok) x 2dc
// part6 aliases part1 -- safe: KB completes before KD.
__global__ __launch_bounds__(256) void kd_slotin(const float* __restrict__ x,
    const float* __restrict__ num, const float* __restrict__ csum_part,
    const float* __restrict__ musum_part, const float* __restrict__ ent_part,
    const float* __restrict__ Wd,
    float* __restrict__ part6, float* __restrict__ disp_out,
    float* __restrict__ loss_out, float* __restrict__ mu_out, float* __restrict__ ent_out){
  const int tc = blockIdx.x >> 1;
  const int dc = blockIdx.x & 1;
  const int tid = threadIdx.x;
  const int d  = dc*1024 + tid*4;
  const int t0 = tc*32;
  __shared__ float4 sN[128];
  if (tid < 128) sN[tid] = ((const float4*)num)[t0*4 + tid];
  __syncthreads();
  float4 acc[16];
  #pragma unroll
  for (int e=0;e<16;e++) acc[e]=make_float4(0,0,0,0);
  #pragma unroll 2
  for (int t=0;t<32;t++){
    const float4 xv = *(const float4*)(x + (size_t)(t0+t)*DIM + d);
    #pragma unroll
    for (int qq=0;qq<4;qq++){
      float4 nq = sN[t*4+qq];
      acc[qq*4+0].x=fmaf(nq.x,xv.x,acc[qq*4+0].x); acc[qq*4+0].y=fmaf(nq.x,xv.y,acc[qq*4+0].y);
      acc[qq*4+0].z=fmaf(nq.x,xv.z,acc[qq*4+0].z); acc[qq*4+0].w=fmaf(nq.x,xv.w,acc[qq*4+0].w);
      acc[qq*4+1].x=fmaf(nq.y,xv.x,acc[qq*4+1].x); acc[qq*4+1].y=fmaf(nq.y,xv.y,acc[qq*4+1].y);
      acc[qq*4+1].z=fmaf(nq.y,xv.z,acc[qq*4+1].z); acc[qq*4+1].w=fmaf(nq.y,xv.w,acc[qq*4+1].w);
      acc[qq*4+2].x=fmaf(nq.z,xv.x,acc[qq*4+2].x); acc[qq*4+2].y=fmaf(nq.z,xv.y,acc[qq*4+2].y);
      acc[qq*4+2].z=fmaf(nq.z,xv.z,acc[qq*4+2].z); acc[qq*4+2].w=fmaf(nq.z,xv.w,acc[qq*4+2].w);
      acc[qq*4+3].x=fmaf(nq.w,xv.x,acc[qq*4+3].x); acc[qq*4+3].y=fmaf(nq.w,xv.y,acc[qq*4+3].y);
      acc[qq*4+3].z=fmaf(nq.w,xv.z,acc[qq*4+3].z); acc[qq*4+3].w=fmaf(nq.w,xv.w,acc[qq*4+3].w);
    }
  }
  #pragma unroll
  for (int e=0;e<16;e++)
    *(float4*)(part6 + ((size_t)tc*16+e)*DIM + d) = acc[e];

  if (dc==0){
    __shared__ float sIv[16][16];
    __shared__ float sInv[16];
    { int g = tid>>4, e = tid&15;
      float v=0.f;
      #pragma unroll
      for (int k=0;k<8;k++) v += csum_part[(g*8+k)*16 + e];
      sIv[g][e]=v; }
    __syncthreads();
    if (tid<16){
      float v=0.f;
      #pragma unroll
      for (int g2=0;g2<16;g2++) v+=sIv[g2][tid];
      sInv[tid]=1.f/v;
    }
    __syncthreads();
    const float* sNf = (const float*)sN;
    const int j = tid*2;
    float2 dv = make_float2(sNf[j]*sInv[j&15], sNf[j+1]*sInv[(j+1)&15]);
    *(float2*)(disp_out + (size_t)t0*16 + j) = dv;

    if (tc==0){
      __shared__ float sq[16][16];
      __shared__ float smu[16];
      __shared__ float sqv[16];
      __shared__ float sqe[16];
      {
        int s = tid>>4, ch = tid&15;
        const float* base = Wd + (size_t)s*DIM + ch*128;
        float qv=0.f;
        for (int ii=0;ii<128;ii+=4){ float4 v=*(const float4*)(base+ii); qv+=v.x+v.y+v.z+v.w; }
        sq[s][ch]=qv;
      }
      if (tid<16){
        float mu=0.f;
        for (int b=0;b<128;b++) mu += musum_part[b*16+tid];
        mu/=8192.f;
        mu_out[tid]=mu; smu[tid]=mu;
      }
      if (tid==32){ float es=0.f; for(int b=0;b<128;b++) es+=ent_part[b]; ent_out[0]=es/8192.f; }
      __syncthreads();
      if (tid<16){ float qv=0.f; for(int s=0;s<16;s++) qv+=sq[s][tid]; sqv[tid]=qv/2048.f; }
      __syncthreads();
      if (tid<16){
        float qm=-INFINITY;
        for (int e=0;e<16;e++) qm=fmaxf(qm,sqv[e]);
        sqe[tid]=expf(sqv[tid]-qm);
      }
      __syncthreads();
      if (tid==0){
        float qs=0.f; for(int e=0;e<16;e++) qs+=sqe[e];
        float loss=0.f; for(int e=0;e<16;e++) loss+=smu[e]*(sqe[e]/qs);
        loss_out[0]=16.f*loss;
      }
    }
  }
}

// KE: sraw[o] = sum_tc part6[tc][o]. grid 1024 x 32 outputs; 8-way tc-split.
__global__ __launch_bounds__(256) void ke_sraw(const float* __restrict__ part6,
    float* __restrict__ sraw){
  const int tid = threadIdx.x;
  const int ol = tid&31, sl = tid>>5;            // 8 slices x 32 tc each
  const int o = blockIdx.x*32 + ol;
  float s=0.f;
  #pragma unroll 8
  for (int k=0;k<32;k++) s += part6[(size_t)(sl*32+k)*32768 + o];
  __shared__ float s2[256];
  s2[tid]=s;
  __syncthreads();
  if (tid<32){
    float t=0.f;
    #pragma unroll
    for (int k=0;k<8;k++) t += s2[k*32+tid];
    sraw[blockIdx.x*32 + tid] = t;
  }
}

// KF: h-GEMV. grid 1024 = 16e x 64hc(16h); 16 waves/CU.
__global__ __launch_bounds__(256) void kf_h(const float* __restrict__ sraw,
    const float* __restrict__ W1, const float* __restrict__ b1,
    const float* __restrict__ csum_part, float* __restrict__ hbuf){
  const int e  = blockIdx.x >> 6;
  const int hc = blockIdx.x & 63;
  const int hbase = hc*16;
  const int tid = threadIdx.x;
  __shared__ float sr[2048];
  __shared__ float sacc[256];
  __shared__ float sIpart[2];
  { const float4* s4 = (const float4*)(sraw + (size_t)e*DIM);
    float4 a = s4[tid*2], b = s4[tid*2+1];
    *(float4*)(&sr[tid*8]) = a; *(float4*)(&sr[tid*8+4]) = b; }
  if (tid < 128){
    float v = csum_part[tid*16 + e];
    #pragma unroll
    for (int o=1;o<64;o<<=1) v += __shfl_xor(v,o,64);
    if ((tid&63)==0) sIpart[tid>>6] = v;
  }
  __syncthreads();
  const int hl = tid&15, ds = tid>>4;            // 16 d-slices of 128
  float acc = 0.f;
  const float* wp = W1 + (size_t)e*DIM*NH + hbase + hl;
  #pragma unroll 16
  for (int i=0;i<128;i++){
    const int dd = ds*128 + i;
    acc = fmaf(sr[dd], wp[(size_t)dd*NH], acc);
  }
  sacc[tid] = acc;
  __syncthreads();
  if (tid < 16){
    float s = 0.f;
    #pragma unroll
    for (int k=0;k<16;k++) s += sacc[k*16 + tid];
    float invs = 1.f/(sIpart[0]+sIpart[1]);
    float pre = invs*s + b1[(size_t)e*NH + hbase + tid];
    hbuf[(size_t)e*NH + hbase + tid] = 0.5f*pre*(1.f+erff(pre*0.70710678118654752f));
  }
}

// KG: slot_out GEMV. grid 1024 = 16e x 64dc(32d); 16 waves/CU.
__global__ __launch_bounds__(256) void kg_so(const float* __restrict__ hbuf,
    const float* __restrict__ W2, const float* __restrict__ b2,
    float* __restrict__ slot_out){
  const int e  = blockIdx.x >> 6;
  const int dc = blockIdx.x & 63;
  const int dbase = dc*32;
  const int tid = threadIdx.x;
  __shared__ float hh[1024];
  __shared__ float sacc[256];
  { const float4* h4 = (const float4*)(hbuf + (size_t)e*NH);
    *(float4*)(&hh[tid*4]) = h4[tid]; }
  __syncthreads();
  const int dl = tid&31, hs = tid>>5;            // 8 h-slices of 128
  float acc = 0.f;
  const float* wp = W2 + (size_t)e*NH*DIM + dbase + dl;
  #pragma unroll 16
  for (int i=0;i<128;i++){
    const int hidx = hs*128 + i;
    acc = fmaf(hh[hidx], wp[(size_t)hidx*DIM], acc);
  }
  sacc[tid] = acc;
  __syncthreads();
  if (tid < 32){
    float s = 0.f;
    #pragma unroll
    for (int k=0;k<8;k++) s += sacc[k*32 + tid];
    slot_out[(size_t)e*DIM + dbase + tid] = s + b2[(size_t)e*DIM + dbase + tid];
  }
}

// KH: out = combine @ slot_out. grid 1024 = 512tb(16tok) x 2dc
__global__ __launch_bounds__(256) void kh_out(const float* __restrict__ slot_out,
    const float* __restrict__ combine, float* __restrict__ out){
  const int tb = blockIdx.x >> 1;
  const int dc = blockIdx.x & 1;
  const int t0 = tb*16;
  const int d  = dc*1024 + threadIdx.x*4;
  float4 sv[16];
  #pragma unroll
  for (int e=0;e<16;e++) sv[e] = *(const float4*)(slot_out + (size_t)e*DIM + d);
  #pragma unroll 2
  for (int t=0;t<16;t++){
    const float* cr = combine + (size_t)(t0+t)*16;
    float4 a = make_float4(0,0,0,0);
    #pragma unroll
    for (int e=0;e<16;e++){
      float c = cr[e];
      a.x=fmaf(c,sv[e].x,a.x); a.y=fmaf(c,sv[e].y,a.y);
      a.z=fmaf(c,sv[e].z,a.z); a.w=fmaf(c,sv[e].w,a.w);
    }
    *(float4*)(out + (size_t)(t0+t)*DIM + d) = a;
  }
}

extern "C" void kernel_launch(void* const* d_in, const int* in_sizes, int n_in,
                              void* d_out, int out_size, void* d_ws, size_t ws_size,
                              hipStream_t stream) {
  const float* x  = (const float*)d_in[0];
  const float* Wd = (const float*)d_in[1];
  const float* W1 = (const float*)d_in[2];
  const float* b1 = (const float*)d_in[3];
  const float* W2 = (const float*)d_in[4];
  const float* b2 = (const float*)d_in[5];
  float* out = (float*)d_out;
  float* ws  = (float*)d_ws;

  float* part1   = ws + OFF_ALIAS;   // [8192][32][16]
  float* part6   = ws + OFF_ALIAS;   // [256][16][2048], after part1 is dead
  float* num     = ws + OFF_NUM;
  float* combine = ws + OFF_COMBINE;
  float* csump   = ws + OFF_CSUM;
  float* musump  = ws + OFF_MUSUM;
  float* entp    = ws + OFF_ENT;
  float* sraw    = ws + OFF_SRAW;
  float* hbuf    = ws + OFF_HBUF;
  float* slot_out= ws + OFF_SLOT;

  ka_logits<<<1024, 256, 0, stream>>>(x, Wd, part1);
  kb_router<<<128, 256, 0, stream>>>(part1, num, csump, combine, out + O_GATE,
                                     out + O_TOPI, out + O_TOPW, musump, entp);
  kd_slotin<<<512, 256, 0, stream>>>(x, num, csump, musump, entp, Wd,
                                     part6, out + O_DISP, out + O_LOSS,
                                     out + O_MU, out + O_ENTR);
  ke_sraw<<<1024, 256, 0, stream>>>(part6, sraw);
  kf_h<<<1024, 256, 0, stream>>>(sraw, W1, b1, csump, hbuf);
  kg_so<<<1024, 256, 0, stream>>>(hbuf, W2, b2, slot_out);
  kh_out<<<1024, 256, 0, stream>>>(slot_out, combine, out + O_OUT);
}